// Round 1
// baseline (556.551 us; speedup 1.0000x reference)
//
#include <hip/hip_runtime.h>
#include <hip/hip_bf16.h>

typedef __attribute__((ext_vector_type(8))) short bf16x8;
typedef __attribute__((ext_vector_type(4))) float f32x4;
typedef unsigned short u16;

#define DEV static __device__ __forceinline__

DEV u16 f2us(float x) {
  __hip_bfloat16 h = __float2bfloat16(x);
  union { __hip_bfloat16 h; u16 u; } c; c.h = h; return c.u;
}
DEV float us2f(u16 u) {
  union { __hip_bfloat16 h; u16 u; } c; c.u = u;
  return __bfloat162float(c.h);
}

// ---------------- problem constants ----------------
// B=2, L=2048, D=1024, H=16, DH=64, P=L+1=2049
constexpr int PE_ROWS = 2096;   // 2048 + 48 band pad, zero-filled past 2048
constexpr int PE_M    = 2176;   // 17 * 128 (GEMM M for PE)

// ---------------- workspace layout (bytes) ----------------
constexpr size_t SZ_QKV  = (size_t)4096 * 1024 * 2;   // 8 MB (bf16 [4096][1024])
constexpr size_t SZ_W    = (size_t)1024 * 1024 * 2;   // 2 MB
constexpr size_t SZ_POSB = (size_t)PE_M * 1024 * 2;
constexpr size_t OFF_QB   = 0;                       // also aliased by attnb later
constexpr size_t OFF_KB   = OFF_QB  + SZ_QKV;
constexpr size_t OFF_VB   = OFF_KB  + SZ_QKV;
constexpr size_t OFF_WQT  = OFF_VB  + SZ_QKV;
constexpr size_t OFF_WKT  = OFF_WQT + SZ_W;
constexpr size_t OFF_WVT  = OFF_WKT + SZ_W;
constexpr size_t OFF_WOT  = OFF_WVT + SZ_W;
constexpr size_t OFF_RKT  = OFF_WOT + SZ_W;
constexpr size_t OFF_POSB = OFF_RKT + SZ_W;
constexpr size_t OFF_QW   = OFF_POSB + SZ_POSB;
constexpr size_t OFF_QR   = OFF_QW  + SZ_QKV;
constexpr size_t OFF_KH   = OFF_QR  + SZ_QKV;
constexpr size_t OFF_VT   = OFF_KH  + SZ_QKV;
constexpr size_t OFF_PEH  = OFF_VT  + SZ_QKV;
constexpr size_t SZ_PEH   = (size_t)16 * PE_ROWS * 64 * 2;
constexpr size_t OFF_ATTNB = OFF_QB;  // alias: qb dead after Q-projection GEMM
// total ≈ 78 MB

// ---------------- conversion kernels ----------------
// fp32 -> bf16, 4 elems/thread; zero-fills [n4in, n4tot)
__global__ __launch_bounds__(256)
void k_f2b4z(const float4* __restrict__ in, u16* __restrict__ out, int n4in, int n4tot) {
  int i = blockIdx.x * 256 + threadIdx.x;
  if (i >= n4tot) return;
  float4 v;
  if (i < n4in) v = in[i];
  else { v.x = v.y = v.z = v.w = 0.f; }
  ushort4 o;
  o.x = f2us(v.x); o.y = f2us(v.y); o.z = f2us(v.z); o.w = f2us(v.w);
  *reinterpret_cast<ushort4*>(out + (size_t)i * 4) = o;
}

// W [1024][1024] fp32 row-major -> Wt[n][k] = W[k][n], bf16
__global__ __launch_bounds__(256)
void k_tconv(const float* __restrict__ in, u16* __restrict__ out) {
  __shared__ float t[32][33];
  const int kb0 = blockIdx.x * 32, nb0 = blockIdx.y * 32;
  const int tx = threadIdx.x & 31, ty = threadIdx.x >> 5;
#pragma unroll
  for (int r = 0; r < 32; r += 8)
    t[ty + r][tx] = in[(size_t)(kb0 + ty + r) * 1024 + nb0 + tx];
  __syncthreads();
#pragma unroll
  for (int r = 0; r < 32; r += 8)
    out[(size_t)(nb0 + ty + r) * 1024 + kb0 + tx] = f2us(t[tx][ty + r]);
}

// r_kernel [16][1024][64] -> Rkt[(h*64+e)][d], bf16
__global__ __launch_bounds__(256)
void k_rkt(const float* __restrict__ rk, u16* __restrict__ out) {
  __shared__ float t[32][33];
  const int h = blockIdx.z;
  const int eb0 = blockIdx.x * 32, db0 = blockIdx.y * 32;
  const int tx = threadIdx.x & 31, ty = threadIdx.x >> 5;
#pragma unroll
  for (int r = 0; r < 32; r += 8)
    t[ty + r][tx] = rk[(size_t)h * 65536 + (size_t)(db0 + ty + r) * 64 + eb0 + tx];
  __syncthreads();
#pragma unroll
  for (int r = 0; r < 32; r += 8)
    out[(size_t)(h * 64 + eb0 + ty + r) * 1024 + db0 + tx] = f2us(t[tx][ty + r]);
}

// ---------------- generic MFMA GEMM ----------------
// C[M][1024] = A[M][1024] @ Bt[1024][1024]^T ; K = N = 1024 fixed.
// EPI 0: +bias, dual-out per-head [B][H][L][64]: out0 = +xb1 (r_w_bias),
//        out1 = +xb2 (r_r_bias)
// EPI 1: +bias, out0 per-head [B][H][L][64]
// EPI 2: +bias, out0 transposed per-head [B][H][64][L]
// EPI 3: out0 = PEh [16][PE_ROWS][64], write guard row < PE_ROWS
// EPI 4: outf fp32 [M][1024] = v + bias
template<int EPI>
__global__ __launch_bounds__(256)
void k_gemm(const u16* __restrict__ A, const u16* __restrict__ Bt,
            const float* __restrict__ bias,
            const float* __restrict__ xb1, const float* __restrict__ xb2,
            u16* __restrict__ out0, u16* __restrict__ out1,
            float* __restrict__ outf)
{
  __shared__ __attribute__((aligned(16))) u16 As[128][40];
  __shared__ __attribute__((aligned(16))) u16 Bs[128][40];
  const int tid  = threadIdx.x;
  const int lane = tid & 63;
  const int wave = tid >> 6;
  const int bm = blockIdx.y * 128;
  const int bn = blockIdx.x * 128;
  const int wr = (wave >> 1) * 64;
  const int wc = (wave & 1) * 64;
  const int fr = lane & 15;
  const int fk = (lane >> 4) * 8;
  const int srow = tid >> 2;
  const int skb  = (tid & 3) * 8;

  f32x4 zero = {0.f, 0.f, 0.f, 0.f};
  f32x4 acc[4][4];
#pragma unroll
  for (int m = 0; m < 4; ++m)
#pragma unroll
    for (int n = 0; n < 4; ++n) acc[m][n] = zero;

  const u16* pa = A  + (size_t)(bm + srow) * 1024 + skb;
  const u16* pb = Bt + (size_t)(bn + srow) * 1024 + skb;

  for (int k0 = 0; k0 < 1024; k0 += 32) {
    *(bf16x8*)(&As[srow][skb])      = *(const bf16x8*)(pa + k0);
    *(bf16x8*)(&As[srow + 64][skb]) = *(const bf16x8*)(pa + (size_t)64 * 1024 + k0);
    *(bf16x8*)(&Bs[srow][skb])      = *(const bf16x8*)(pb + k0);
    *(bf16x8*)(&Bs[srow + 64][skb]) = *(const bf16x8*)(pb + (size_t)64 * 1024 + k0);
    __syncthreads();
    bf16x8 af[4], bfv[4];
#pragma unroll
    for (int m = 0; m < 4; ++m) af[m]  = *(const bf16x8*)(&As[wr + m * 16 + fr][fk]);
#pragma unroll
    for (int n = 0; n < 4; ++n) bfv[n] = *(const bf16x8*)(&Bs[wc + n * 16 + fr][fk]);
#pragma unroll
    for (int m = 0; m < 4; ++m)
#pragma unroll
      for (int n = 0; n < 4; ++n)
        acc[m][n] = __builtin_amdgcn_mfma_f32_16x16x32_bf16(af[m], bfv[n], acc[m][n], 0, 0, 0);
    __syncthreads();
  }

#pragma unroll
  for (int m = 0; m < 4; ++m)
#pragma unroll
    for (int n = 0; n < 4; ++n)
#pragma unroll
      for (int r = 0; r < 4; ++r) {
        const int grow = bm + wr + m * 16 + (lane >> 4) * 4 + r;
        const int gcol = bn + wc + n * 16 + fr;
        float v = acc[m][n][r];
        if (EPI == 0) {
          v += bias[gcol];
          const int b_ = grow >> 11, l_ = grow & 2047;
          const int h_ = gcol >> 6,  e_ = gcol & 63;
          const size_t o = (((size_t)(b_ * 16 + h_) * 2048 + l_) << 6) + e_;
          out0[o] = f2us(v + xb1[gcol]);
          out1[o] = f2us(v + xb2[gcol]);
        } else if (EPI == 1) {
          v += bias[gcol];
          const int b_ = grow >> 11, l_ = grow & 2047;
          const int h_ = gcol >> 6,  e_ = gcol & 63;
          const size_t o = (((size_t)(b_ * 16 + h_) * 2048 + l_) << 6) + e_;
          out0[o] = f2us(v);
        } else if (EPI == 2) {
          v += bias[gcol];
          const int b_ = grow >> 11, l_ = grow & 2047;
          const int h_ = gcol >> 6,  e_ = gcol & 63;
          const size_t o = (((size_t)(b_ * 16 + h_) * 64 + e_) << 11) + l_;
          out0[o] = f2us(v);
        } else if (EPI == 3) {
          if (grow < PE_ROWS) {
            const int h_ = gcol >> 6, e_ = gcol & 63;
            const size_t o = ((size_t)h_ * PE_ROWS + grow) * 64 + e_;
            out0[o] = f2us(v);
          }
        } else {
          outf[(size_t)grow * 1024 + gcol] = v + bias[gcol];
        }
      }
}

// ---------------- fused rel-position causal attention ----------------
// grid (32 qb, 16 h, 2 b), block 256 = 4 independent waves, 16 q-rows/wave.
__global__ __launch_bounds__(256)
void k_attn(const u16* __restrict__ Qw, const u16* __restrict__ Qr,
            const u16* __restrict__ Kh, const u16* __restrict__ Vt,
            const u16* __restrict__ PEh, u16* __restrict__ attnb)
{
  const int qb = blockIdx.x, h = blockIdx.y, b = blockIdx.z;
  const int wave = threadIdx.x >> 6, lane = threadIdx.x & 63;
  const int q0 = qb * 64 + wave * 16;
  const int fr  = lane & 15;
  const int fko = (lane >> 4) * 8;
  const int rg  = (lane >> 4) * 4;

  const size_t hb = (size_t)(b * 16 + h);
  const u16* Qw_h = Qw + hb * 2048 * 64;
  const u16* Qr_h = Qr + hb * 2048 * 64;
  const u16* K_h  = Kh + hb * 2048 * 64;
  const u16* V_h  = Vt + hb * 64 * 2048;
  const u16* PE_h = PEh + (size_t)h * PE_ROWS * 64;

  bf16x8 aqw[2], aqr[2];
  {
    const u16* p = Qw_h + (size_t)(q0 + fr) * 64 + fko;
    aqw[0] = *(const bf16x8*)(p);
    aqw[1] = *(const bf16x8*)(p + 32);
    const u16* p2 = Qr_h + (size_t)(q0 + fr) * 64 + fko;
    aqr[0] = *(const bf16x8*)(p2);
    aqr[1] = *(const bf16x8*)(p2 + 32);
  }

  __shared__ float Eld[4][16][49];
  __shared__ __attribute__((aligned(16))) u16 Pld[4][16][40];
  float (*E)[49] = Eld[wave];
  u16   (*P)[40] = Pld[wave];

  f32x4 zero = {0.f, 0.f, 0.f, 0.f};
  f32x4 Oacc[4];
#pragma unroll
  for (int et = 0; et < 4; ++et) Oacc[et] = zero;
  float m[4], ls[4];
#pragma unroll
  for (int r = 0; r < 4; ++r) { m[r] = -INFINITY; ls[r] = 0.f; }

  for (int c0 = 0; c0 <= q0 + 15; c0 += 32) {
    // ---- content scores: two 16-col subtiles, K=64 ----
    f32x4 sc[2];
#pragma unroll
    for (int cs = 0; cs < 2; ++cs) {
      const u16* kp = K_h + (size_t)(c0 + cs * 16 + fr) * 64 + fko;
      bf16x8 kf0 = *(const bf16x8*)(kp);
      bf16x8 kf1 = *(const bf16x8*)(kp + 32);
      f32x4 s = zero;
      s = __builtin_amdgcn_mfma_f32_16x16x32_bf16(aqw[0], kf0, s, 0, 0, 0);
      s = __builtin_amdgcn_mfma_f32_16x16x32_bf16(aqw[1], kf1, s, 0, 0, 0);
      sc[cs] = s;
    }
    // ---- rel band E[qq][t] = Qr . PE[Jb + t], t in [0,48) ----
    const int Jb = 2048 + c0 - q0 - 15;
#pragma unroll
    for (int et = 0; et < 3; ++et) {
      const u16* pp = PE_h + (size_t)(Jb + et * 16 + fr) * 64 + fko;
      bf16x8 pf0 = *(const bf16x8*)(pp);
      bf16x8 pf1 = *(const bf16x8*)(pp + 32);
      f32x4 e = zero;
      e = __builtin_amdgcn_mfma_f32_16x16x32_bf16(aqr[0], pf0, e, 0, 0, 0);
      e = __builtin_amdgcn_mfma_f32_16x16x32_bf16(aqr[1], pf1, e, 0, 0, 0);
#pragma unroll
      for (int r = 0; r < 4; ++r) E[rg + r][et * 16 + fr] = e[r];
    }
    // ---- assemble S = scale*(content + rel-gather), causal mask ----
    float sv[2][4];
#pragma unroll
    for (int cs = 0; cs < 2; ++cs)
#pragma unroll
      for (int r = 0; r < 4; ++r) {
        const int qq = rg + r;
        const int cc = cs * 16 + fr;
        float x = (sc[cs][r] + E[qq][cc - qq + 15]) * 0.125f;
        if (c0 + cc > q0 + qq) x = -1e30f;
        sv[cs][r] = x;
      }
    // ---- online softmax over 32 cols ----
    float al[4];
#pragma unroll
    for (int r = 0; r < 4; ++r) {
      float mr = fmaxf(sv[0][r], sv[1][r]);
#pragma unroll
      for (int off = 8; off >= 1; off >>= 1)
        mr = fmaxf(mr, __shfl_xor(mr, off));
      const float mn = fmaxf(m[r], mr);
      al[r] = __expf(m[r] - mn);
      m[r] = mn;
    }
    float rs[4] = {0.f, 0.f, 0.f, 0.f};
#pragma unroll
    for (int cs = 0; cs < 2; ++cs)
#pragma unroll
      for (int r = 0; r < 4; ++r) {
        float p = __expf(sv[cs][r] - m[r]);
        u16 pu = f2us(p);
        rs[r] += us2f(pu);           // denom matches bf16-rounded numerator
        P[rg + r][cs * 16 + fr] = pu;
      }
#pragma unroll
    for (int r = 0; r < 4; ++r) {
      float s = rs[r];
#pragma unroll
      for (int off = 8; off >= 1; off >>= 1)
        s += __shfl_xor(s, off);
      ls[r] = ls[r] * al[r] + s;
    }
#pragma unroll
    for (int et = 0; et < 4; ++et)
#pragma unroll
      for (int r = 0; r < 4; ++r) Oacc[et][r] *= al[r];
    // ---- PV: K=32, A = P from LDS, B = Vt rows (contiguous) ----
    bf16x8 pa = *(const bf16x8*)(&P[fr][fko]);
#pragma unroll
    for (int et = 0; et < 4; ++et) {
      const u16* vp = V_h + (size_t)(et * 16 + fr) * 2048 + c0 + fko;
      bf16x8 vf = *(const bf16x8*)(vp);
      Oacc[et] = __builtin_amdgcn_mfma_f32_16x16x32_bf16(pa, vf, Oacc[et], 0, 0, 0);
    }
  }
  // ---- finalize ----
  float inv[4];
#pragma unroll
  for (int r = 0; r < 4; ++r) inv[r] = 1.f / ls[r];
#pragma unroll
  for (int et = 0; et < 4; ++et)
#pragma unroll
    for (int r = 0; r < 4; ++r) {
      const int q = q0 + rg + r;
      const int e = et * 16 + fr;
      attnb[(size_t)(b * 2048 + q) * 1024 + h * 64 + e] = f2us(Oacc[et][r] * inv[r]);
    }
}

// ---------------- launch ----------------
extern "C" void kernel_launch(void* const* d_in, const int* in_sizes, int n_in,
                              void* d_out, int out_size, void* d_ws, size_t ws_size,
                              hipStream_t stream)
{
  const float* q   = (const float*)d_in[0];
  const float* k   = (const float*)d_in[1];
  const float* v   = (const float*)d_in[2];
  const float* pos = (const float*)d_in[3];
  const float* Wq  = (const float*)d_in[4];
  const float* bq  = (const float*)d_in[5];
  const float* Wk  = (const float*)d_in[6];
  const float* bk  = (const float*)d_in[7];
  const float* Wv  = (const float*)d_in[8];
  const float* bv  = (const float*)d_in[9];
  const float* Wo  = (const float*)d_in[10];
  const float* bo  = (const float*)d_in[11];
  const float* rwb = (const float*)d_in[12];
  const float* rrb = (const float*)d_in[13];
  const float* rk  = (const float*)d_in[14];

  char* ws = (char*)d_ws;
  u16* qb    = (u16*)(ws + OFF_QB);
  u16* kb    = (u16*)(ws + OFF_KB);
  u16* vb    = (u16*)(ws + OFF_VB);
  u16* Wqt   = (u16*)(ws + OFF_WQT);
  u16* Wkt   = (u16*)(ws + OFF_WKT);
  u16* Wvt   = (u16*)(ws + OFF_WVT);
  u16* Wot   = (u16*)(ws + OFF_WOT);
  u16* Rkt   = (u16*)(ws + OFF_RKT);
  u16* posb  = (u16*)(ws + OFF_POSB);
  u16* Qw    = (u16*)(ws + OFF_QW);
  u16* Qr    = (u16*)(ws + OFF_QR);
  u16* Kh    = (u16*)(ws + OFF_KH);
  u16* Vt    = (u16*)(ws + OFF_VT);
  u16* PEh   = (u16*)(ws + OFF_PEH);
  u16* attnb = (u16*)(ws + OFF_ATTNB);   // aliases qb (dead after Q GEMM)
  float* outf = (float*)d_out;

  // fp32 -> bf16 conversions
  k_f2b4z<<<dim3(4096), 256, 0, stream>>>((const float4*)q, qb, 1048576, 1048576);
  k_f2b4z<<<dim3(4096), 256, 0, stream>>>((const float4*)k, kb, 1048576, 1048576);
  k_f2b4z<<<dim3(4096), 256, 0, stream>>>((const float4*)v, vb, 1048576, 1048576);
  k_f2b4z<<<dim3(2176), 256, 0, stream>>>((const float4*)pos, posb,
                                          (2049 * 1024) / 4, (PE_M * 1024) / 4);
  k_tconv<<<dim3(32, 32), 256, 0, stream>>>(Wq, Wqt);
  k_tconv<<<dim3(32, 32), 256, 0, stream>>>(Wk, Wkt);
  k_tconv<<<dim3(32, 32), 256, 0, stream>>>(Wv, Wvt);
  k_tconv<<<dim3(32, 32), 256, 0, stream>>>(Wo, Wot);
  k_rkt<<<dim3(2, 32, 16), 256, 0, stream>>>(rk, Rkt);

  // projections
  k_gemm<0><<<dim3(8, 32), 256, 0, stream>>>(qb, Wqt, bq, rwb, rrb, Qw, Qr, nullptr);
  k_gemm<1><<<dim3(8, 32), 256, 0, stream>>>(kb, Wkt, bk, nullptr, nullptr, Kh, nullptr, nullptr);
  k_gemm<2><<<dim3(8, 32), 256, 0, stream>>>(vb, Wvt, bv, nullptr, nullptr, Vt, nullptr, nullptr);
  k_gemm<3><<<dim3(8, PE_M / 128), 256, 0, stream>>>(posb, Rkt, nullptr, nullptr, nullptr, PEh, nullptr, nullptr);

  // fused attention
  k_attn<<<dim3(32, 16, 2), 256, 0, stream>>>(Qw, Qr, Kh, Vt, PEh, attnb);

  // output projection (fp32 out)
  k_gemm<4><<<dim3(8, 32), 256, 0, stream>>>(attnb, Wot, bo, nullptr, nullptr, nullptr, nullptr, outf);
}

// Round 2
// 480.425 us; speedup vs baseline: 1.1585x; 1.1585x over previous
//
#include <hip/hip_runtime.h>
#include <hip/hip_bf16.h>

typedef __attribute__((ext_vector_type(8))) short bf16x8;
typedef __attribute__((ext_vector_type(4))) float f32x4;
typedef unsigned short u16;

#define DEV static __device__ __forceinline__

DEV u16 f2us(float x) {
  __hip_bfloat16 h = __float2bfloat16(x);
  union { __hip_bfloat16 h; u16 u; } c; c.h = h; return c.u;
}
DEV float us2f(u16 u) {
  union { __hip_bfloat16 h; u16 u; } c; c.u = u;
  return __bfloat162float(c.h);
}

// ---------------- problem constants ----------------
// B=2, L=2048, D=1024, H=16, DH=64, P=L+1=2049
constexpr int PE_ROWS = 2096;   // 2048 + 48 band pad, zero-filled past 2048
constexpr int PE_M    = 2176;   // 17 * 128 (GEMM M for PE)

// ---------------- workspace layout (bytes) ----------------
constexpr size_t SZ_QKV  = (size_t)4096 * 1024 * 2;   // 8 MB (bf16 [4096][1024])
constexpr size_t SZ_W    = (size_t)1024 * 1024 * 2;   // 2 MB
constexpr size_t SZ_POSB = (size_t)PE_M * 1024 * 2;
constexpr size_t OFF_QB   = 0;                       // also aliased by attnb later
constexpr size_t OFF_KB   = OFF_QB  + SZ_QKV;
constexpr size_t OFF_VB   = OFF_KB  + SZ_QKV;
constexpr size_t OFF_WQT  = OFF_VB  + SZ_QKV;
constexpr size_t OFF_WKT  = OFF_WQT + SZ_W;
constexpr size_t OFF_WVT  = OFF_WKT + SZ_W;
constexpr size_t OFF_WOT  = OFF_WVT + SZ_W;
constexpr size_t OFF_RKT  = OFF_WOT + SZ_W;
constexpr size_t OFF_POSB = OFF_RKT + SZ_W;
constexpr size_t OFF_QW   = OFF_POSB + SZ_POSB;
constexpr size_t OFF_QR   = OFF_QW  + SZ_QKV;
constexpr size_t OFF_KH   = OFF_QR  + SZ_QKV;
constexpr size_t OFF_VT   = OFF_KH  + SZ_QKV;
constexpr size_t OFF_PEH  = OFF_VT  + SZ_QKV;
constexpr size_t SZ_PEH   = (size_t)16 * PE_ROWS * 64 * 2;
constexpr size_t OFF_ATTNB = OFF_QB;  // alias: qb dead after Q-projection GEMM

// ---------------- conversion kernels ----------------
__global__ __launch_bounds__(256)
void k_f2b4z(const float4* __restrict__ in, u16* __restrict__ out, int n4in, int n4tot) {
  int i = blockIdx.x * 256 + threadIdx.x;
  if (i >= n4tot) return;
  float4 v;
  if (i < n4in) v = in[i];
  else { v.x = v.y = v.z = v.w = 0.f; }
  ushort4 o;
  o.x = f2us(v.x); o.y = f2us(v.y); o.z = f2us(v.z); o.w = f2us(v.w);
  *reinterpret_cast<ushort4*>(out + (size_t)i * 4) = o;
}

__global__ __launch_bounds__(256)
void k_tconv(const float* __restrict__ in, u16* __restrict__ out) {
  __shared__ float t[32][33];
  const int kb0 = blockIdx.x * 32, nb0 = blockIdx.y * 32;
  const int tx = threadIdx.x & 31, ty = threadIdx.x >> 5;
#pragma unroll
  for (int r = 0; r < 32; r += 8)
    t[ty + r][tx] = in[(size_t)(kb0 + ty + r) * 1024 + nb0 + tx];
  __syncthreads();
#pragma unroll
  for (int r = 0; r < 32; r += 8)
    out[(size_t)(nb0 + ty + r) * 1024 + kb0 + tx] = f2us(t[tx][ty + r]);
}

__global__ __launch_bounds__(256)
void k_rkt(const float* __restrict__ rk, u16* __restrict__ out) {
  __shared__ float t[32][33];
  const int h = blockIdx.z;
  const int eb0 = blockIdx.x * 32, db0 = blockIdx.y * 32;
  const int tx = threadIdx.x & 31, ty = threadIdx.x >> 5;
#pragma unroll
  for (int r = 0; r < 32; r += 8)
    t[ty + r][tx] = rk[(size_t)h * 65536 + (size_t)(db0 + ty + r) * 64 + eb0 + tx];
  __syncthreads();
#pragma unroll
  for (int r = 0; r < 32; r += 8)
    out[(size_t)(h * 64 + eb0 + ty + r) * 1024 + db0 + tx] = f2us(t[tx][ty + r]);
}

// ---------------- fused Q/K/V/PE projection GEMM ----------------
// blockIdx.z selects the GEMM; all share C[M][1024] = A[M][1024] @ Bt^T.
struct ProjPtrs {
  const u16 *A0, *A1, *A2, *A3;
  const u16 *B0, *B1, *B2, *B3;
  const float *bias0, *bias1, *bias2;
  const float *rwb, *rrb;
  u16 *Qw, *Qr, *Kh, *Vt, *PEh;
};

__global__ __launch_bounds__(256)
void k_gemm_proj(ProjPtrs pp)
{
  const int z = blockIdx.z;
  if (z == 3 && blockIdx.y >= PE_M / 128) return;
  const u16* A  = (z == 0) ? pp.A0 : (z == 1) ? pp.A1 : (z == 2) ? pp.A2 : pp.A3;
  const u16* Bt = (z == 0) ? pp.B0 : (z == 1) ? pp.B1 : (z == 2) ? pp.B2 : pp.B3;

  __shared__ __attribute__((aligned(16))) u16 As[128][40];
  __shared__ __attribute__((aligned(16))) u16 Bs[128][40];
  const int tid  = threadIdx.x;
  const int lane = tid & 63;
  const int wave = tid >> 6;
  const int bm = blockIdx.y * 128;
  const int bn = blockIdx.x * 128;
  const int wr = (wave >> 1) * 64;
  const int wc = (wave & 1) * 64;
  const int fr = lane & 15;
  const int fk = (lane >> 4) * 8;
  const int srow = tid >> 2;
  const int skb  = (tid & 3) * 8;

  f32x4 zero = {0.f, 0.f, 0.f, 0.f};
  f32x4 acc[4][4];
#pragma unroll
  for (int m = 0; m < 4; ++m)
#pragma unroll
    for (int n = 0; n < 4; ++n) acc[m][n] = zero;

  const u16* pa = A  + (size_t)(bm + srow) * 1024 + skb;
  const u16* pb = Bt + (size_t)(bn + srow) * 1024 + skb;

  for (int k0 = 0; k0 < 1024; k0 += 32) {
    *(bf16x8*)(&As[srow][skb])      = *(const bf16x8*)(pa + k0);
    *(bf16x8*)(&As[srow + 64][skb]) = *(const bf16x8*)(pa + (size_t)64 * 1024 + k0);
    *(bf16x8*)(&Bs[srow][skb])      = *(const bf16x8*)(pb + k0);
    *(bf16x8*)(&Bs[srow + 64][skb]) = *(const bf16x8*)(pb + (size_t)64 * 1024 + k0);
    __syncthreads();
    bf16x8 af[4], bfv[4];
#pragma unroll
    for (int m = 0; m < 4; ++m) af[m]  = *(const bf16x8*)(&As[wr + m * 16 + fr][fk]);
#pragma unroll
    for (int n = 0; n < 4; ++n) bfv[n] = *(const bf16x8*)(&Bs[wc + n * 16 + fr][fk]);
#pragma unroll
    for (int m = 0; m < 4; ++m)
#pragma unroll
      for (int n = 0; n < 4; ++n)
        acc[m][n] = __builtin_amdgcn_mfma_f32_16x16x32_bf16(af[m], bfv[n], acc[m][n], 0, 0, 0);
    __syncthreads();
  }

#pragma unroll
  for (int m = 0; m < 4; ++m)
#pragma unroll
    for (int n = 0; n < 4; ++n)
#pragma unroll
      for (int r = 0; r < 4; ++r) {
        const int grow = bm + wr + m * 16 + (lane >> 4) * 4 + r;
        const int gcol = bn + wc + n * 16 + fr;
        float v = acc[m][n][r];
        const int b_ = grow >> 11, l_ = grow & 2047;
        const int h_ = gcol >> 6,  e_ = gcol & 63;
        if (z == 0) {
          v += pp.bias0[gcol];
          const size_t o = (((size_t)(b_ * 16 + h_) * 2048 + l_) << 6) + e_;
          pp.Qw[o] = f2us(v + pp.rwb[gcol]);
          pp.Qr[o] = f2us(v + pp.rrb[gcol]);
        } else if (z == 1) {
          v += pp.bias1[gcol];
          const size_t o = (((size_t)(b_ * 16 + h_) * 2048 + l_) << 6) + e_;
          pp.Kh[o] = f2us(v);
        } else if (z == 2) {
          v += pp.bias2[gcol];
          const size_t o = (((size_t)(b_ * 16 + h_) * 64 + e_) << 11) + l_;
          pp.Vt[o] = f2us(v);
        } else {
          if (grow < PE_ROWS) {
            const size_t o = ((size_t)h_ * PE_ROWS + grow) * 64 + e_;
            pp.PEh[o] = f2us(v);
          }
        }
      }
}

// ---------------- output projection GEMM (fp32 out) ----------------
__global__ __launch_bounds__(256)
void k_gemm_o(const u16* __restrict__ A, const u16* __restrict__ Bt,
              const float* __restrict__ bias, float* __restrict__ outf)
{
  __shared__ __attribute__((aligned(16))) u16 As[128][40];
  __shared__ __attribute__((aligned(16))) u16 Bs[128][40];
  const int tid  = threadIdx.x;
  const int lane = tid & 63;
  const int wave = tid >> 6;
  const int bm = blockIdx.y * 128;
  const int bn = blockIdx.x * 128;
  const int wr = (wave >> 1) * 64;
  const int wc = (wave & 1) * 64;
  const int fr = lane & 15;
  const int fk = (lane >> 4) * 8;
  const int srow = tid >> 2;
  const int skb  = (tid & 3) * 8;

  f32x4 zero = {0.f, 0.f, 0.f, 0.f};
  f32x4 acc[4][4];
#pragma unroll
  for (int m = 0; m < 4; ++m)
#pragma unroll
    for (int n = 0; n < 4; ++n) acc[m][n] = zero;

  const u16* pa = A  + (size_t)(bm + srow) * 1024 + skb;
  const u16* pb = Bt + (size_t)(bn + srow) * 1024 + skb;

  for (int k0 = 0; k0 < 1024; k0 += 32) {
    *(bf16x8*)(&As[srow][skb])      = *(const bf16x8*)(pa + k0);
    *(bf16x8*)(&As[srow + 64][skb]) = *(const bf16x8*)(pa + (size_t)64 * 1024 + k0);
    *(bf16x8*)(&Bs[srow][skb])      = *(const bf16x8*)(pb + k0);
    *(bf16x8*)(&Bs[srow + 64][skb]) = *(const bf16x8*)(pb + (size_t)64 * 1024 + k0);
    __syncthreads();
    bf16x8 af[4], bfv[4];
#pragma unroll
    for (int m = 0; m < 4; ++m) af[m]  = *(const bf16x8*)(&As[wr + m * 16 + fr][fk]);
#pragma unroll
    for (int n = 0; n < 4; ++n) bfv[n] = *(const bf16x8*)(&Bs[wc + n * 16 + fr][fk]);
#pragma unroll
    for (int m = 0; m < 4; ++m)
#pragma unroll
      for (int n = 0; n < 4; ++n)
        acc[m][n] = __builtin_amdgcn_mfma_f32_16x16x32_bf16(af[m], bfv[n], acc[m][n], 0, 0, 0);
    __syncthreads();
  }

#pragma unroll
  for (int m = 0; m < 4; ++m)
#pragma unroll
    for (int n = 0; n < 4; ++n)
#pragma unroll
      for (int r = 0; r < 4; ++r) {
        const int grow = bm + wr + m * 16 + (lane >> 4) * 4 + r;
        const int gcol = bn + wc + n * 16 + fr;
        outf[(size_t)grow * 1024 + gcol] = acc[m][n][r] + bias[gcol];
      }
}

// ---------------- fused rel-position causal attention ----------------
// grid (32 qb, 16 h, 2 b), block 256 = 4 independent waves, 16 q-rows/wave.
// Pipelined: K double-buffered, PE band ring-carried (+2 prefetch tiles),
// V issued at step top / consumed at step end. E-gather via shuffles.
__global__ __launch_bounds__(256, 2)
void k_attn(const u16* __restrict__ Qw, const u16* __restrict__ Qr,
            const u16* __restrict__ Kh, const u16* __restrict__ Vt,
            const u16* __restrict__ PEh, u16* __restrict__ attnb)
{
  const int qb = blockIdx.x, h = blockIdx.y, b = blockIdx.z;
  const int wave = threadIdx.x >> 6, lane = threadIdx.x & 63;
  const int q0 = qb * 64 + wave * 16;
  const int fr  = lane & 15;
  const int fko = (lane >> 4) * 8;
  const int rg  = (lane >> 4) * 4;

  const size_t hb = (size_t)(b * 16 + h);
  const u16* Qw_h = Qw + hb * (2048 * 64);
  const u16* Qr_h = Qr + hb * (2048 * 64);
  const u16* K_h  = Kh + hb * (2048 * 64);
  const u16* V_h  = Vt + hb * (64 * 2048);
  const u16* PE_h = PEh + (size_t)h * (PE_ROWS * 64);

  bf16x8 aqw[2], aqr[2];
  {
    const u16* p = Qw_h + (size_t)(q0 + fr) * 64 + fko;
    aqw[0] = *(const bf16x8*)(p);
    aqw[1] = *(const bf16x8*)(p + 32);
    const u16* p2 = Qr_h + (size_t)(q0 + fr) * 64 + fko;
    aqr[0] = *(const bf16x8*)(p2);
    aqr[1] = *(const bf16x8*)(p2 + 32);
  }

  __shared__ __attribute__((aligned(16))) u16 Pld[4][16][40];
  u16 (*P)[40] = Pld[wave];

  const f32x4 zero = {0.f, 0.f, 0.f, 0.f};
  f32x4 Oacc[4];
#pragma unroll
  for (int et = 0; et < 4; ++et) Oacc[et] = zero;
  float m[4], ls[4];
#pragma unroll
  for (int r = 0; r < 4; ++r) { m[r] = -INFINITY; ls[r] = 0.f; }

  // prologue: K and PE-band fragments for step c0=0
  bf16x8 kc[4], pf[3][2];
  {
    const u16* kp = K_h + (size_t)fr * 64 + fko;
    kc[0] = *(const bf16x8*)(kp);
    kc[1] = *(const bf16x8*)(kp + 32);
    kc[2] = *(const bf16x8*)(kp + 1024);
    kc[3] = *(const bf16x8*)(kp + 1024 + 32);
    const int Jb0 = 2048 - q0 - 15;
#pragma unroll
    for (int et = 0; et < 3; ++et) {
      const u16* pp = PE_h + (size_t)(Jb0 + et * 16 + fr) * 64 + fko;
      pf[et][0] = *(const bf16x8*)(pp);
      pf[et][1] = *(const bf16x8*)(pp + 32);
    }
  }

  for (int c0 = 0; c0 <= q0 + 15; c0 += 32) {
    // V for current step (consumed at end of step)
    bf16x8 vf[4];
#pragma unroll
    for (int et = 0; et < 4; ++et)
      vf[et] = *(const bf16x8*)(V_h + (size_t)(et * 16 + fr) * 2048 + c0 + fko);
    // prefetch next step's K + 2 new PE band tiles
    const bool more = (c0 + 32 <= q0 + 15);
    bf16x8 kn[4], pn[2][2];
    if (more) {
      const u16* kp = K_h + (size_t)(c0 + 32 + fr) * 64 + fko;
      kn[0] = *(const bf16x8*)(kp);
      kn[1] = *(const bf16x8*)(kp + 32);
      kn[2] = *(const bf16x8*)(kp + 1024);
      kn[3] = *(const bf16x8*)(kp + 1024 + 32);
      const int Jc = 2048 + c0 - q0 - 15;
#pragma unroll
      for (int t = 0; t < 2; ++t) {
        const u16* pp = PE_h + (size_t)(Jc + 48 + t * 16 + fr) * 64 + fko;
        pn[t][0] = *(const bf16x8*)(pp);
        pn[t][1] = *(const bf16x8*)(pp + 32);
      }
    }
    // ---- rel band E tiles (PE frags already in regs) ----
    f32x4 e[3];
#pragma unroll
    for (int et = 0; et < 3; ++et) {
      f32x4 t = zero;
      t = __builtin_amdgcn_mfma_f32_16x16x32_bf16(aqr[0], pf[et][0], t, 0, 0, 0);
      t = __builtin_amdgcn_mfma_f32_16x16x32_bf16(aqr[1], pf[et][1], t, 0, 0, 0);
      e[et] = t;
    }
    // ---- content scores ----
    f32x4 sc[2];
    {
      f32x4 t = zero;
      t = __builtin_amdgcn_mfma_f32_16x16x32_bf16(aqw[0], kc[0], t, 0, 0, 0);
      t = __builtin_amdgcn_mfma_f32_16x16x32_bf16(aqw[1], kc[1], t, 0, 0, 0);
      sc[0] = t;
      t = zero;
      t = __builtin_amdgcn_mfma_f32_16x16x32_bf16(aqw[0], kc[2], t, 0, 0, 0);
      t = __builtin_amdgcn_mfma_f32_16x16x32_bf16(aqw[1], kc[3], t, 0, 0, 0);
      sc[1] = t;
    }
    // ---- diagonal E-gather via shuffle + assemble S ----
    // S[qq][cc] needs E[qq][t*], t* = cc - qq + 15 = fr + w, w = cs*16+15-qq.
    // a = w>>4 == cs (static); src lane (same hi-group) at tc=(fr+w)&15 sends
    // e[cs] if tc >= (w&15) else e[cs+1].
    float sv[2][4];
#pragma unroll
    for (int cs = 0; cs < 2; ++cs)
#pragma unroll
      for (int r = 0; r < 4; ++r) {
        const int qq = rg + r;
        const int w  = cs * 16 + 15 - qq;
        const float vsend = (fr >= (w & 15)) ? e[cs][r] : e[cs + 1][r];
        const int srcl = (lane & 48) | ((fr + w) & 15);
        const float ev = __shfl(vsend, srcl);
        float x = (sc[cs][r] + ev) * 0.125f;
        if (c0 + cs * 16 + fr > q0 + qq) x = -1e30f;
        sv[cs][r] = x;
      }
    // ---- online softmax over 32 cols ----
    float al[4];
#pragma unroll
    for (int r = 0; r < 4; ++r) {
      float mr = fmaxf(sv[0][r], sv[1][r]);
#pragma unroll
      for (int off = 8; off >= 1; off >>= 1)
        mr = fmaxf(mr, __shfl_xor(mr, off));
      const float mn = fmaxf(m[r], mr);
      al[r] = __expf(m[r] - mn);
      m[r] = mn;
    }
    float rs[4] = {0.f, 0.f, 0.f, 0.f};
#pragma unroll
    for (int cs = 0; cs < 2; ++cs)
#pragma unroll
      for (int r = 0; r < 4; ++r) {
        float pval = __expf(sv[cs][r] - m[r]);
        u16 pu = f2us(pval);
        rs[r] += us2f(pu);
        P[rg + r][cs * 16 + fr] = pu;
      }
#pragma unroll
    for (int r = 0; r < 4; ++r) {
      float s = rs[r];
#pragma unroll
      for (int off = 8; off >= 1; off >>= 1)
        s += __shfl_xor(s, off);
      ls[r] = ls[r] * al[r] + s;
    }
#pragma unroll
    for (int et = 0; et < 4; ++et)
#pragma unroll
      for (int r = 0; r < 4; ++r) Oacc[et][r] *= al[r];
    // ---- PV ----
    bf16x8 pa = *(const bf16x8*)(&P[fr][fko]);
#pragma unroll
    for (int et = 0; et < 4; ++et)
      Oacc[et] = __builtin_amdgcn_mfma_f32_16x16x32_bf16(pa, vf[et], Oacc[et], 0, 0, 0);
    // ---- rotate pipeline buffers ----
    if (more) {
#pragma unroll
      for (int i = 0; i < 4; ++i) kc[i] = kn[i];
      pf[0][0] = pf[2][0]; pf[0][1] = pf[2][1];
      pf[1][0] = pn[0][0]; pf[1][1] = pn[0][1];
      pf[2][0] = pn[1][0]; pf[2][1] = pn[1][1];
    }
  }
  // ---- finalize ----
  float inv[4];
#pragma unroll
  for (int r = 0; r < 4; ++r) inv[r] = 1.f / ls[r];
#pragma unroll
  for (int et = 0; et < 4; ++et)
#pragma unroll
    for (int r = 0; r < 4; ++r) {
      const int q = q0 + rg + r;
      const int e = et * 16 + fr;
      attnb[(size_t)(b * 2048 + q) * 1024 + h * 64 + e] = f2us(Oacc[et][r] * inv[r]);
    }
}

// ---------------- launch ----------------
extern "C" void kernel_launch(void* const* d_in, const int* in_sizes, int n_in,
                              void* d_out, int out_size, void* d_ws, size_t ws_size,
                              hipStream_t stream)
{
  const float* q   = (const float*)d_in[0];
  const float* k   = (const float*)d_in[1];
  const float* v   = (const float*)d_in[2];
  const float* pos = (const float*)d_in[3];
  const float* Wq  = (const float*)d_in[4];
  const float* bq  = (const float*)d_in[5];
  const float* Wk  = (const float*)d_in[6];
  const float* bk  = (const float*)d_in[7];
  const float* Wv  = (const float*)d_in[8];
  const float* bv  = (const float*)d_in[9];
  const float* Wo  = (const float*)d_in[10];
  const float* bo  = (const float*)d_in[11];
  const float* rwb = (const float*)d_in[12];
  const float* rrb = (const float*)d_in[13];
  const float* rk  = (const float*)d_in[14];

  char* ws = (char*)d_ws;
  u16* qb    = (u16*)(ws + OFF_QB);
  u16* kb    = (u16*)(ws + OFF_KB);
  u16* vb    = (u16*)(ws + OFF_VB);
  u16* Wqt   = (u16*)(ws + OFF_WQT);
  u16* Wkt   = (u16*)(ws + OFF_WKT);
  u16* Wvt   = (u16*)(ws + OFF_WVT);
  u16* Wot   = (u16*)(ws + OFF_WOT);
  u16* Rkt   = (u16*)(ws + OFF_RKT);
  u16* posb  = (u16*)(ws + OFF_POSB);
  u16* Qw    = (u16*)(ws + OFF_QW);
  u16* Qr    = (u16*)(ws + OFF_QR);
  u16* Kh    = (u16*)(ws + OFF_KH);
  u16* Vt    = (u16*)(ws + OFF_VT);
  u16* PEh   = (u16*)(ws + OFF_PEH);
  u16* attnb = (u16*)(ws + OFF_ATTNB);   // aliases qb (dead after Q GEMM)
  float* outf = (float*)d_out;

  // fp32 -> bf16 conversions
  k_f2b4z<<<dim3(4096), 256, 0, stream>>>((const float4*)q, qb, 1048576, 1048576);
  k_f2b4z<<<dim3(4096), 256, 0, stream>>>((const float4*)k, kb, 1048576, 1048576);
  k_f2b4z<<<dim3(4096), 256, 0, stream>>>((const float4*)v, vb, 1048576, 1048576);
  k_f2b4z<<<dim3(2176), 256, 0, stream>>>((const float4*)pos, posb,
                                          (2049 * 1024) / 4, (PE_M * 1024) / 4);
  k_tconv<<<dim3(32, 32), 256, 0, stream>>>(Wq, Wqt);
  k_tconv<<<dim3(32, 32), 256, 0, stream>>>(Wk, Wkt);
  k_tconv<<<dim3(32, 32), 256, 0, stream>>>(Wv, Wvt);
  k_tconv<<<dim3(32, 32), 256, 0, stream>>>(Wo, Wot);
  k_rkt<<<dim3(2, 32, 16), 256, 0, stream>>>(rk, Rkt);

  // fused Q/K/V/PE projections (one launch, ~3.5 blocks/CU)
  ProjPtrs pp;
  pp.A0 = qb;  pp.A1 = kb;  pp.A2 = vb;  pp.A3 = posb;
  pp.B0 = Wqt; pp.B1 = Wkt; pp.B2 = Wvt; pp.B3 = Rkt;
  pp.bias0 = bq; pp.bias1 = bk; pp.bias2 = bv;
  pp.rwb = rwb; pp.rrb = rrb;
  pp.Qw = Qw; pp.Qr = Qr; pp.Kh = Kh; pp.Vt = Vt; pp.PEh = PEh;
  k_gemm_proj<<<dim3(8, 32, 4), 256, 0, stream>>>(pp);

  // fused attention
  k_attn<<<dim3(32, 16, 2), 256, 0, stream>>>(Qw, Qr, Kh, Vt, PEh, attnb);

  // output projection (fp32 out)
  k_gemm_o<<<dim3(8, 32), 256, 0, stream>>>(attnb, Wot, bo, outf);
}

// Round 3
// 279.746 us; speedup vs baseline: 1.9895x; 1.7174x over previous
//
#include <hip/hip_runtime.h>
#include <hip/hip_bf16.h>

typedef __attribute__((ext_vector_type(8))) short bf16x8;
typedef __attribute__((ext_vector_type(4))) float f32x4;
typedef __attribute__((ext_vector_type(16))) float f32x16;
typedef unsigned short u16;
typedef unsigned int u32;

#define DEV static __device__ __forceinline__

DEV u16 f2us(float x) {
  __hip_bfloat16 h = __float2bfloat16(x);
  union { __hip_bfloat16 h; u16 u; } c; c.h = h; return c.u;
}
DEV float us2f(u16 u) {
  union { __hip_bfloat16 h; u16 u; } c; c.u = u;
  return __bfloat162float(c.h);
}
DEV f32x16 mfma32(bf16x8 a, bf16x8 b, f32x16 c) {
  return __builtin_amdgcn_mfma_f32_32x32x16_bf16(a, b, c, 0, 0, 0);
}

// ---------------- problem constants ----------------
// B=2, L=2048, D=1024, H=16, DH=64, P=L+1=2049
constexpr int PE_ROWS = 2096;   // 2048 + band pad, zero-filled past 2048
constexpr int PE_M    = 2176;   // 17 * 128 (GEMM M for PE)

// ---------------- workspace layout (bytes) ----------------
constexpr size_t SZ_QKV  = (size_t)4096 * 1024 * 2;   // 8 MB (bf16 [4096][1024])
constexpr size_t SZ_W    = (size_t)1024 * 1024 * 2;   // 2 MB
constexpr size_t SZ_POSB = (size_t)PE_M * 1024 * 2;
constexpr size_t OFF_QB   = 0;                       // also aliased by attnb later
constexpr size_t OFF_KB   = OFF_QB  + SZ_QKV;
constexpr size_t OFF_VB   = OFF_KB  + SZ_QKV;
constexpr size_t OFF_WQT  = OFF_VB  + SZ_QKV;
constexpr size_t OFF_WKT  = OFF_WQT + SZ_W;
constexpr size_t OFF_WVT  = OFF_WKT + SZ_W;
constexpr size_t OFF_WOT  = OFF_WVT + SZ_W;
constexpr size_t OFF_RKT  = OFF_WOT + SZ_W;
constexpr size_t OFF_POSB = OFF_RKT + SZ_W;
constexpr size_t OFF_QW   = OFF_POSB + SZ_POSB;
constexpr size_t OFF_QR   = OFF_QW  + SZ_QKV;
constexpr size_t OFF_KH   = OFF_QR  + SZ_QKV;
constexpr size_t OFF_VT   = OFF_KH  + SZ_QKV;
constexpr size_t OFF_PEH  = OFF_VT  + SZ_QKV;
constexpr size_t OFF_ATTNB = OFF_QB;  // alias: qb dead after Q-projection GEMM

// ---------------- conversion kernels ----------------
__global__ __launch_bounds__(256)
void k_f2b4z(const float4* __restrict__ in, u16* __restrict__ out, int n4in, int n4tot) {
  int i = blockIdx.x * 256 + threadIdx.x;
  if (i >= n4tot) return;
  float4 v;
  if (i < n4in) v = in[i];
  else { v.x = v.y = v.z = v.w = 0.f; }
  ushort4 o;
  o.x = f2us(v.x); o.y = f2us(v.y); o.z = f2us(v.z); o.w = f2us(v.w);
  *reinterpret_cast<ushort4*>(out + (size_t)i * 4) = o;
}

__global__ __launch_bounds__(256)
void k_tconv(const float* __restrict__ in, u16* __restrict__ out) {
  __shared__ float t[32][33];
  const int kb0 = blockIdx.x * 32, nb0 = blockIdx.y * 32;
  const int tx = threadIdx.x & 31, ty = threadIdx.x >> 5;
#pragma unroll
  for (int r = 0; r < 32; r += 8)
    t[ty + r][tx] = in[(size_t)(kb0 + ty + r) * 1024 + nb0 + tx];
  __syncthreads();
#pragma unroll
  for (int r = 0; r < 32; r += 8)
    out[(size_t)(nb0 + ty + r) * 1024 + kb0 + tx] = f2us(t[tx][ty + r]);
}

__global__ __launch_bounds__(256)
void k_rkt(const float* __restrict__ rk, u16* __restrict__ out) {
  __shared__ float t[32][33];
  const int h = blockIdx.z;
  const int eb0 = blockIdx.x * 32, db0 = blockIdx.y * 32;
  const int tx = threadIdx.x & 31, ty = threadIdx.x >> 5;
#pragma unroll
  for (int r = 0; r < 32; r += 8)
    t[ty + r][tx] = rk[(size_t)h * 65536 + (size_t)(db0 + ty + r) * 64 + eb0 + tx];
  __syncthreads();
#pragma unroll
  for (int r = 0; r < 32; r += 8)
    out[(size_t)(h * 64 + eb0 + ty + r) * 1024 + db0 + tx] = f2us(t[tx][ty + r]);
}

// ---------------- fused Q/K/V/PE projection GEMM ----------------
struct ProjPtrs {
  const u16 *A0, *A1, *A2, *A3;
  const u16 *B0, *B1, *B2, *B3;
  const float *bias0, *bias1, *bias2;
  const float *rwb, *rrb;
  u16 *Qw, *Qr, *Kh, *Vt, *PEh;
};

__global__ __launch_bounds__(256)
void k_gemm_proj(ProjPtrs pp)
{
  const int z = blockIdx.z;
  if (z == 3 && blockIdx.y >= PE_M / 128) return;
  const u16* A  = (z == 0) ? pp.A0 : (z == 1) ? pp.A1 : (z == 2) ? pp.A2 : pp.A3;
  const u16* Bt = (z == 0) ? pp.B0 : (z == 1) ? pp.B1 : (z == 2) ? pp.B2 : pp.B3;

  __shared__ __attribute__((aligned(16))) u16 As[128][40];
  __shared__ __attribute__((aligned(16))) u16 Bs[128][40];
  const int tid  = threadIdx.x;
  const int lane = tid & 63;
  const int wave = tid >> 6;
  const int bm = blockIdx.y * 128;
  const int bn = blockIdx.x * 128;
  const int wr = (wave >> 1) * 64;
  const int wc = (wave & 1) * 64;
  const int fr = lane & 15;
  const int fk = (lane >> 4) * 8;
  const int srow = tid >> 2;
  const int skb  = (tid & 3) * 8;

  f32x4 zero = {0.f, 0.f, 0.f, 0.f};
  f32x4 acc[4][4];
#pragma unroll
  for (int m = 0; m < 4; ++m)
#pragma unroll
    for (int n = 0; n < 4; ++n) acc[m][n] = zero;

  const u16* pa = A  + (size_t)(bm + srow) * 1024 + skb;
  const u16* pb = Bt + (size_t)(bn + srow) * 1024 + skb;

  for (int k0 = 0; k0 < 1024; k0 += 32) {
    *(bf16x8*)(&As[srow][skb])      = *(const bf16x8*)(pa + k0);
    *(bf16x8*)(&As[srow + 64][skb]) = *(const bf16x8*)(pa + (size_t)64 * 1024 + k0);
    *(bf16x8*)(&Bs[srow][skb])      = *(const bf16x8*)(pb + k0);
    *(bf16x8*)(&Bs[srow + 64][skb]) = *(const bf16x8*)(pb + (size_t)64 * 1024 + k0);
    __syncthreads();
    bf16x8 af[4], bfv[4];
#pragma unroll
    for (int m = 0; m < 4; ++m) af[m]  = *(const bf16x8*)(&As[wr + m * 16 + fr][fk]);
#pragma unroll
    for (int n = 0; n < 4; ++n) bfv[n] = *(const bf16x8*)(&Bs[wc + n * 16 + fr][fk]);
#pragma unroll
    for (int m = 0; m < 4; ++m)
#pragma unroll
      for (int n = 0; n < 4; ++n)
        acc[m][n] = __builtin_amdgcn_mfma_f32_16x16x32_bf16(af[m], bfv[n], acc[m][n], 0, 0, 0);
    __syncthreads();
  }

#pragma unroll
  for (int m = 0; m < 4; ++m)
#pragma unroll
    for (int n = 0; n < 4; ++n)
#pragma unroll
      for (int r = 0; r < 4; ++r) {
        const int grow = bm + wr + m * 16 + (lane >> 4) * 4 + r;
        const int gcol = bn + wc + n * 16 + fr;
        float v = acc[m][n][r];
        const int b_ = grow >> 11, l_ = grow & 2047;
        const int h_ = gcol >> 6,  e_ = gcol & 63;
        if (z == 0) {
          v += pp.bias0[gcol];
          const size_t o = (((size_t)(b_ * 16 + h_) * 2048 + l_) << 6) + e_;
          pp.Qw[o] = f2us(v + pp.rwb[gcol]);
          pp.Qr[o] = f2us(v + pp.rrb[gcol]);
        } else if (z == 1) {
          v += pp.bias1[gcol];
          const size_t o = (((size_t)(b_ * 16 + h_) * 2048 + l_) << 6) + e_;
          pp.Kh[o] = f2us(v);
        } else if (z == 2) {
          v += pp.bias2[gcol];
          const size_t o = (((size_t)(b_ * 16 + h_) * 64 + e_) << 11) + l_;
          pp.Vt[o] = f2us(v);
        } else {
          if (grow < PE_ROWS) {
            const size_t o = ((size_t)h_ * PE_ROWS + grow) * 64 + e_;
            pp.PEh[o] = f2us(v);
          }
        }
      }
}

// ---------------- output projection GEMM (fp32 out) ----------------
__global__ __launch_bounds__(256)
void k_gemm_o(const u16* __restrict__ A, const u16* __restrict__ Bt,
              const float* __restrict__ bias, float* __restrict__ outf)
{
  __shared__ __attribute__((aligned(16))) u16 As[128][40];
  __shared__ __attribute__((aligned(16))) u16 Bs[128][40];
  const int tid  = threadIdx.x;
  const int lane = tid & 63;
  const int wave = tid >> 6;
  const int bm = blockIdx.y * 128;
  const int bn = blockIdx.x * 128;
  const int wr = (wave >> 1) * 64;
  const int wc = (wave & 1) * 64;
  const int fr = lane & 15;
  const int fk = (lane >> 4) * 8;
  const int srow = tid >> 2;
  const int skb  = (tid & 3) * 8;

  f32x4 zero = {0.f, 0.f, 0.f, 0.f};
  f32x4 acc[4][4];
#pragma unroll
  for (int m = 0; m < 4; ++m)
#pragma unroll
    for (int n = 0; n < 4; ++n) acc[m][n] = zero;

  const u16* pa = A  + (size_t)(bm + srow) * 1024 + skb;
  const u16* pb = Bt + (size_t)(bn + srow) * 1024 + skb;

  for (int k0 = 0; k0 < 1024; k0 += 32) {
    *(bf16x8*)(&As[srow][skb])      = *(const bf16x8*)(pa + k0);
    *(bf16x8*)(&As[srow + 64][skb]) = *(const bf16x8*)(pa + (size_t)64 * 1024 + k0);
    *(bf16x8*)(&Bs[srow][skb])      = *(const bf16x8*)(pb + k0);
    *(bf16x8*)(&Bs[srow + 64][skb]) = *(const bf16x8*)(pb + (size_t)64 * 1024 + k0);
    __syncthreads();
    bf16x8 af[4], bfv[4];
#pragma unroll
    for (int m = 0; m < 4; ++m) af[m]  = *(const bf16x8*)(&As[wr + m * 16 + fr][fk]);
#pragma unroll
    for (int n = 0; n < 4; ++n) bfv[n] = *(const bf16x8*)(&Bs[wc + n * 16 + fr][fk]);
#pragma unroll
    for (int m = 0; m < 4; ++m)
#pragma unroll
      for (int n = 0; n < 4; ++n)
        acc[m][n] = __builtin_amdgcn_mfma_f32_16x16x32_bf16(af[m], bfv[n], acc[m][n], 0, 0, 0);
    __syncthreads();
  }

#pragma unroll
  for (int m = 0; m < 4; ++m)
#pragma unroll
    for (int n = 0; n < 4; ++n)
#pragma unroll
      for (int r = 0; r < 4; ++r) {
        const int grow = bm + wr + m * 16 + (lane >> 4) * 4 + r;
        const int gcol = bn + wc + n * 16 + fr;
        outf[(size_t)grow * 1024 + gcol] = acc[m][n][r] + bias[gcol];
      }
}

// ---------------- fused rel-position causal attention (32x32 swapped) ----------
// grid (16, 16 h, 2 b), block 256 = 4 waves. Wave w of block j handles q-tile
// qt in {2j, 2j+1, 62-2j, 63-2j} (32 q-rows) -> equal work per block.
// S^T = mfma(K, Q): lane owns q = lane&31, 32 kv values split with lane^32.
// Rel band E^T = mfma(PE, Qr) staged in per-wave LDS [32 q][96 t] f32,
// tile2 acc carried as next step's tile0. P -> PV B-frags via pack + shfl_xor32.
__global__ __launch_bounds__(256, 2)
void k_attn(const u16* __restrict__ Qw, const u16* __restrict__ Qr,
            const u16* __restrict__ Kh, const u16* __restrict__ Vt,
            const u16* __restrict__ PEh, u16* __restrict__ attnb)
{
  const int jb = blockIdx.x, h = blockIdx.y, b = blockIdx.z;
  const int wave = threadIdx.x >> 6, lane = threadIdx.x & 63;
  const int l31 = lane & 31, hi = lane >> 5;
  const int qt = (wave == 0) ? 2 * jb : (wave == 1) ? 2 * jb + 1
               : (wave == 2) ? 62 - 2 * jb : 63 - 2 * jb;
  const int q0 = qt * 32;

  const size_t hb = (size_t)(b * 16 + h);
  const u16* Qw_h = Qw + hb * (2048 * 64);
  const u16* Qr_h = Qr + hb * (2048 * 64);
  const u16* K_h  = Kh + hb * (2048 * 64);
  const u16* V_h  = Vt + hb * (64 * 2048);
  const u16* PE_h = PEh + (size_t)h * (PE_ROWS * 64);

  __shared__ float Elds_all[4][32][100];
  float (*Elds)[100] = Elds_all[wave];

  // Q fragments (B-operand: col = lane&31 = q, k = 8*hi + e)
  bf16x8 qwf[4], qrf[4];
#pragma unroll
  for (int kk = 0; kk < 4; ++kk) {
    qwf[kk] = *(const bf16x8*)(Qw_h + (size_t)(q0 + l31) * 64 + kk * 16 + hi * 8);
    qrf[kk] = *(const bf16x8*)(Qr_h + (size_t)(q0 + l31) * 64 + kk * 16 + hi * 8);
  }

  // prologue: carried E tile (rows [Jb0, Jb0+32))
  const int Jb0 = 2017 - q0;
  f32x16 carry = {};
#pragma unroll
  for (int kk = 0; kk < 4; ++kk) {
    bf16x8 pe = *(const bf16x8*)(PE_h + (size_t)(Jb0 + l31) * 64 + kk * 16 + hi * 8);
    carry = mfma32(pe, qrf[kk], carry);
  }

  f32x16 Oac[2] = {};
  float mrun = -1e30f, ls = 0.f;

  for (int c0 = 0; c0 <= q0 + 31; c0 += 64) {
    const int Jb = Jb0 + c0;
    // ---- E band: tile0 from carry, tiles 1,2 fresh ----
#pragma unroll
    for (int g = 0; g < 4; ++g) {
      float4 w4 = {carry[4 * g], carry[4 * g + 1], carry[4 * g + 2], carry[4 * g + 3]};
      *(float4*)&Elds[l31][g * 8 + hi * 4] = w4;
    }
#pragma unroll
    for (int tau = 1; tau <= 2; ++tau) {
      f32x16 eacc = {};
#pragma unroll
      for (int kk = 0; kk < 4; ++kk) {
        bf16x8 pe = *(const bf16x8*)(PE_h + (size_t)(Jb + tau * 32 + l31) * 64 + kk * 16 + hi * 8);
        eacc = mfma32(pe, qrf[kk], eacc);
      }
#pragma unroll
      for (int g = 0; g < 4; ++g) {
        float4 w4 = {eacc[4 * g], eacc[4 * g + 1], eacc[4 * g + 2], eacc[4 * g + 3]};
        *(float4*)&Elds[l31][tau * 32 + g * 8 + hi * 4] = w4;
      }
      if (tau == 2) carry = eacc;
    }

    const bool act1 = (c0 + 32 <= q0 + 31);
    // ---- QK^T (swapped): S^T[kv][q] ----
    f32x16 s0 = {}, s1 = {};
#pragma unroll
    for (int kk = 0; kk < 4; ++kk) {
      bf16x8 kf = *(const bf16x8*)(K_h + (size_t)(c0 + l31) * 64 + kk * 16 + hi * 8);
      s0 = mfma32(kf, qwf[kk], s0);
    }
    if (act1) {
#pragma unroll
      for (int kk = 0; kk < 4; ++kk) {
        bf16x8 kf = *(const bf16x8*)(K_h + (size_t)(c0 + 32 + l31) * 64 + kk * 16 + hi * 8);
        s1 = mfma32(kf, qwf[kk], s1);
      }
    }
    // ---- S assemble: +E (diag read), scale, mask ----
    const bool mk0 = (c0 + 31 > q0);
    const bool mk1 = (c0 + 63 > q0);
#pragma unroll
    for (int r = 0; r < 16; ++r) {
      const int pat = (r & 3) + 8 * (r >> 2) + 4 * hi;
      float e = Elds[l31][pat + 31 - l31];
      float x = (s0[r] + e) * 0.125f;
      if (mk0 && (c0 + pat > q0 + l31)) x = -1e30f;
      s0[r] = x;
    }
    if (act1) {
#pragma unroll
      for (int r = 0; r < 16; ++r) {
        const int pat = (r & 3) + 8 * (r >> 2) + 4 * hi;
        float e = Elds[l31][32 + pat + 31 - l31];
        float x = (s1[r] + e) * 0.125f;
        if (mk1 && (c0 + 32 + pat > q0 + l31)) x = -1e30f;
        s1[r] = x;
      }
    }
    // ---- online softmax (in-lane + one cross-half shuffle) ----
    float mx = s0[0];
#pragma unroll
    for (int r = 1; r < 16; ++r) mx = fmaxf(mx, s0[r]);
    if (act1) {
#pragma unroll
      for (int r = 0; r < 16; ++r) mx = fmaxf(mx, s1[r]);
    }
    mx = fmaxf(mx, __shfl_xor(mx, 32));
    const float mn = fmaxf(mrun, mx);
    const float al = __expf(mrun - mn);
    mrun = mn;

    float rsum = 0.f;
    u32 w0a[8], w1a[8];
#pragma unroll
    for (int g = 0; g < 8; ++g) {
      float pa = __expf(s0[2 * g] - mn);
      float pb = __expf(s0[2 * g + 1] - mn);
      u16 ua = f2us(pa), ub = f2us(pb);
      rsum += us2f(ua) + us2f(ub);
      w0a[g] = (u32)ua | ((u32)ub << 16);
    }
    if (act1) {
#pragma unroll
      for (int g = 0; g < 8; ++g) {
        float pa = __expf(s1[2 * g] - mn);
        float pb = __expf(s1[2 * g + 1] - mn);
        u16 ua = f2us(pa), ub = f2us(pb);
        rsum += us2f(ua) + us2f(ub);
        w1a[g] = (u32)ua | ((u32)ub << 16);
      }
    }
    ls = ls * al + rsum + __shfl_xor(rsum, 32);
    Oac[0] *= al;
    Oac[1] *= al;

    // ---- PV: build B-frags via half-exchange, A = Vt rows ----
#define PV_KT(WARR, KT)                                                        \
    {                                                                          \
      _Pragma("unroll")                                                        \
      for (int kvs = 0; kvs < 2; ++kvs) {                                      \
        u32 snd0 = hi ? WARR[4 * kvs]     : WARR[4 * kvs + 2];                 \
        u32 snd1 = hi ? WARR[4 * kvs + 1] : WARR[4 * kvs + 3];                 \
        u32 r0 = (u32)__shfl_xor((int)snd0, 32);                               \
        u32 r1 = (u32)__shfl_xor((int)snd1, 32);                               \
        union { u32 u[4]; bf16x8 v; } pf;                                      \
        pf.u[0] = hi ? r0 : WARR[4 * kvs];                                     \
        pf.u[1] = hi ? r1 : WARR[4 * kvs + 1];                                 \
        pf.u[2] = hi ? WARR[4 * kvs + 2] : r0;                                 \
        pf.u[3] = hi ? WARR[4 * kvs + 3] : r1;                                 \
        _Pragma("unroll")                                                      \
        for (int dt = 0; dt < 2; ++dt) {                                       \
          bf16x8 vf = *(const bf16x8*)(V_h + (size_t)(dt * 32 + l31) * 2048    \
                                       + c0 + KT * 32 + kvs * 16 + hi * 8);    \
          Oac[dt] = mfma32(vf, pf.v, Oac[dt]);                                 \
        }                                                                      \
      }                                                                        \
    }
    PV_KT(w0a, 0)
    if (act1) PV_KT(w1a, 1)
#undef PV_KT
  }

  // ---- finalize: O^T[d][q] -> attnb[b][q][h*64+d] ----
  const float invl = 1.f / ls;
  const size_t orow = ((size_t)(b * 2048 + q0 + l31)) * 1024 + h * 64;
#pragma unroll
  for (int dt = 0; dt < 2; ++dt)
#pragma unroll
    for (int g = 0; g < 4; ++g) {
      ushort4 st;
      st.x = f2us(Oac[dt][4 * g + 0] * invl);
      st.y = f2us(Oac[dt][4 * g + 1] * invl);
      st.z = f2us(Oac[dt][4 * g + 2] * invl);
      st.w = f2us(Oac[dt][4 * g + 3] * invl);
      *(ushort4*)(attnb + orow + dt * 32 + g * 8 + hi * 4) = st;
    }
}

// ---------------- launch ----------------
extern "C" void kernel_launch(void* const* d_in, const int* in_sizes, int n_in,
                              void* d_out, int out_size, void* d_ws, size_t ws_size,
                              hipStream_t stream)
{
  const float* q   = (const float*)d_in[0];
  const float* k   = (const float*)d_in[1];
  const float* v   = (const float*)d_in[2];
  const float* pos = (const float*)d_in[3];
  const float* Wq  = (const float*)d_in[4];
  const float* bq  = (const float*)d_in[5];
  const float* Wk  = (const float*)d_in[6];
  const float* bk  = (const float*)d_in[7];
  const float* Wv  = (const float*)d_in[8];
  const float* bv  = (const float*)d_in[9];
  const float* Wo  = (const float*)d_in[10];
  const float* bo  = (const float*)d_in[11];
  const float* rwb = (const float*)d_in[12];
  const float* rrb = (const float*)d_in[13];
  const float* rk  = (const float*)d_in[14];

  char* ws = (char*)d_ws;
  u16* qb    = (u16*)(ws + OFF_QB);
  u16* kb    = (u16*)(ws + OFF_KB);
  u16* vb    = (u16*)(ws + OFF_VB);
  u16* Wqt   = (u16*)(ws + OFF_WQT);
  u16* Wkt   = (u16*)(ws + OFF_WKT);
  u16* Wvt   = (u16*)(ws + OFF_WVT);
  u16* Wot   = (u16*)(ws + OFF_WOT);
  u16* Rkt   = (u16*)(ws + OFF_RKT);
  u16* posb  = (u16*)(ws + OFF_POSB);
  u16* Qw    = (u16*)(ws + OFF_QW);
  u16* Qr    = (u16*)(ws + OFF_QR);
  u16* Kh    = (u16*)(ws + OFF_KH);
  u16* Vt    = (u16*)(ws + OFF_VT);
  u16* PEh   = (u16*)(ws + OFF_PEH);
  u16* attnb = (u16*)(ws + OFF_ATTNB);   // aliases qb (dead after Q GEMM)
  float* outf = (float*)d_out;

  // fp32 -> bf16 conversions
  k_f2b4z<<<dim3(4096), 256, 0, stream>>>((const float4*)q, qb, 1048576, 1048576);
  k_f2b4z<<<dim3(4096), 256, 0, stream>>>((const float4*)k, kb, 1048576, 1048576);
  k_f2b4z<<<dim3(4096), 256, 0, stream>>>((const float4*)v, vb, 1048576, 1048576);
  k_f2b4z<<<dim3(2176), 256, 0, stream>>>((const float4*)pos, posb,
                                          (2049 * 1024) / 4, (PE_M * 1024) / 4);
  k_tconv<<<dim3(32, 32), 256, 0, stream>>>(Wq, Wqt);
  k_tconv<<<dim3(32, 32), 256, 0, stream>>>(Wk, Wkt);
  k_tconv<<<dim3(32, 32), 256, 0, stream>>>(Wv, Wvt);
  k_tconv<<<dim3(32, 32), 256, 0, stream>>>(Wo, Wot);
  k_rkt<<<dim3(2, 32, 16), 256, 0, stream>>>(rk, Rkt);

  // fused Q/K/V/PE projections
  ProjPtrs pp;
  pp.A0 = qb;  pp.A1 = kb;  pp.A2 = vb;  pp.A3 = posb;
  pp.B0 = Wqt; pp.B1 = Wkt; pp.B2 = Wvt; pp.B3 = Rkt;
  pp.bias0 = bq; pp.bias1 = bk; pp.bias2 = bv;
  pp.rwb = rwb; pp.rrb = rrb;
  pp.Qw = Qw; pp.Qr = Qr; pp.Kh = Kh; pp.Vt = Vt; pp.PEh = PEh;
  k_gemm_proj<<<dim3(8, 32, 4), 256, 0, stream>>>(pp);

  // fused attention (balanced 32x32 swapped-operand form)
  k_attn<<<dim3(16, 16, 2), 256, 0, stream>>>(Qw, Qr, Kh, Vt, PEh, attnb);

  // output projection (fp32 out)
  k_gemm_o<<<dim3(8, 32), 256, 0, stream>>>(attnb, Wot, bo, outf);
}

// Round 4
// 266.604 us; speedup vs baseline: 2.0876x; 1.0493x over previous
//
#include <hip/hip_runtime.h>
#include <hip/hip_bf16.h>

typedef __attribute__((ext_vector_type(8))) short bf16x8;
typedef __attribute__((ext_vector_type(4))) float f32x4;
typedef __attribute__((ext_vector_type(16))) float f32x16;
typedef unsigned short u16;
typedef unsigned int u32;

#define DEV static __device__ __forceinline__

DEV u16 f2us(float x) {
  __hip_bfloat16 h = __float2bfloat16(x);
  union { __hip_bfloat16 h; u16 u; } c; c.h = h; return c.u;
}
DEV float us2f(u16 u) {
  union { __hip_bfloat16 h; u16 u; } c; c.u = u;
  return __bfloat162float(c.h);
}
DEV f32x16 mfma32(bf16x8 a, bf16x8 b, f32x16 c) {
  return __builtin_amdgcn_mfma_f32_32x32x16_bf16(a, b, c, 0, 0, 0);
}
// async global->LDS, 16B per lane; LDS dst = wave-uniform base + lane*16
DEV void gl16(const u16* g, u16* l) {
  __builtin_amdgcn_global_load_lds(
      (const __attribute__((address_space(1))) unsigned int*)(g),
      (__attribute__((address_space(3))) unsigned int*)(l), 16, 0, 0);
}

// ---------------- problem constants ----------------
// B=2, L=2048, D=1024, H=16, DH=64, P=L+1=2049
constexpr int PE_ROWS = 2144;   // 2048 + 96 band pad (max row read = 2143)
constexpr int PE_M    = 2176;   // 17 * 128 (GEMM M for PE)

// ---------------- workspace layout (bytes) ----------------
constexpr size_t SZ_QKV  = (size_t)4096 * 1024 * 2;   // 8 MB (bf16 [4096][1024])
constexpr size_t SZ_W    = (size_t)1024 * 1024 * 2;   // 2 MB
constexpr size_t SZ_POSB = (size_t)PE_M * 1024 * 2;
constexpr size_t OFF_QB   = 0;                       // also aliased by attnb later
constexpr size_t OFF_KB   = OFF_QB  + SZ_QKV;
constexpr size_t OFF_VB   = OFF_KB  + SZ_QKV;
constexpr size_t OFF_WQT  = OFF_VB  + SZ_QKV;
constexpr size_t OFF_WKT  = OFF_WQT + SZ_W;
constexpr size_t OFF_WVT  = OFF_WKT + SZ_W;
constexpr size_t OFF_WOT  = OFF_WVT + SZ_W;
constexpr size_t OFF_RKT  = OFF_WOT + SZ_W;
constexpr size_t OFF_POSB = OFF_RKT + SZ_W;
constexpr size_t OFF_QW   = OFF_POSB + SZ_POSB;
constexpr size_t OFF_QR   = OFF_QW  + SZ_QKV;
constexpr size_t OFF_KH   = OFF_QR  + SZ_QKV;
constexpr size_t OFF_VT   = OFF_KH  + SZ_QKV;
constexpr size_t OFF_PEH  = OFF_VT  + SZ_QKV;
constexpr size_t OFF_ATTNB = OFF_QB;  // alias: qb dead after Q-projection GEMM

// ---------------- conversion kernels ----------------
__global__ __launch_bounds__(256)
void k_f2b4z(const float4* __restrict__ in, u16* __restrict__ out, int n4in, int n4tot) {
  int i = blockIdx.x * 256 + threadIdx.x;
  if (i >= n4tot) return;
  float4 v;
  if (i < n4in) v = in[i];
  else { v.x = v.y = v.z = v.w = 0.f; }
  ushort4 o;
  o.x = f2us(v.x); o.y = f2us(v.y); o.z = f2us(v.z); o.w = f2us(v.w);
  *reinterpret_cast<ushort4*>(out + (size_t)i * 4) = o;
}

__global__ __launch_bounds__(256)
void k_tconv(const float* __restrict__ in, u16* __restrict__ out) {
  __shared__ float t[32][33];
  const int kb0 = blockIdx.x * 32, nb0 = blockIdx.y * 32;
  const int tx = threadIdx.x & 31, ty = threadIdx.x >> 5;
#pragma unroll
  for (int r = 0; r < 32; r += 8)
    t[ty + r][tx] = in[(size_t)(kb0 + ty + r) * 1024 + nb0 + tx];
  __syncthreads();
#pragma unroll
  for (int r = 0; r < 32; r += 8)
    out[(size_t)(nb0 + ty + r) * 1024 + kb0 + tx] = f2us(t[tx][ty + r]);
}

__global__ __launch_bounds__(256)
void k_rkt(const float* __restrict__ rk, u16* __restrict__ out) {
  __shared__ float t[32][33];
  const int h = blockIdx.z;
  const int eb0 = blockIdx.x * 32, db0 = blockIdx.y * 32;
  const int tx = threadIdx.x & 31, ty = threadIdx.x >> 5;
#pragma unroll
  for (int r = 0; r < 32; r += 8)
    t[ty + r][tx] = rk[(size_t)h * 65536 + (size_t)(db0 + ty + r) * 64 + eb0 + tx];
  __syncthreads();
#pragma unroll
  for (int r = 0; r < 32; r += 8)
    out[(size_t)(h * 64 + eb0 + ty + r) * 1024 + db0 + tx] = f2us(t[tx][ty + r]);
}

// ---------------- fused Q/K/V/PE projection GEMM (m97 structure) -------------
struct ProjPtrs {
  const u16 *A0, *A1, *A2, *A3;
  const u16 *B0, *B1, *B2, *B3;
  const float *bias0, *bias1, *bias2;
  const float *rwb, *rrb;
  u16 *Qw, *Qr, *Kh, *Vt, *PEh;
};

__global__ __launch_bounds__(256)
void k_gemm_proj(ProjPtrs pp)
{
  const int z = blockIdx.z;
  if (z == 3 && blockIdx.y >= PE_M / 128) return;
  const u16* A  = (z == 0) ? pp.A0 : (z == 1) ? pp.A1 : (z == 2) ? pp.A2 : pp.A3;
  const u16* Bt = (z == 0) ? pp.B0 : (z == 1) ? pp.B1 : (z == 2) ? pp.B2 : pp.B3;

  __shared__ __attribute__((aligned(16))) u16 As[128 * 32];
  __shared__ __attribute__((aligned(16))) u16 Bs[128 * 32];
  const int tid  = threadIdx.x;
  const int lane = tid & 63;
  const int wave = tid >> 6;
  const int bm = blockIdx.y * 128;
  const int bn = blockIdx.x * 128;
  const int wr = (wave >> 1) * 64;
  const int wc = (wave & 1) * 64;
  const int fr = lane & 15;
  const int fk = (lane >> 4) * 8;

  f32x4 zero = {0.f, 0.f, 0.f, 0.f};
  f32x4 acc[4][4];
#pragma unroll
  for (int m = 0; m < 4; ++m)
#pragma unroll
    for (int n = 0; n < 4; ++n) acc[m][n] = zero;

  // staging: wave w stages 16-row chunks {2w, 2w+1} of A and B.
  const int cA = wave * 2;
  const u16* gA = A  + (size_t)(bm + cA * 16 + (lane >> 2)) * 1024 + (lane & 3) * 8;
  const u16* gB = Bt + (size_t)(bn + cA * 16 + (lane >> 2)) * 1024 + (lane & 3) * 8;
  u16* lA = As + cA * 512;
  u16* lB = Bs + cA * 512;

  for (int k0 = 0; k0 < 1024; k0 += 32) {
    gl16(gA + k0, lA);
    gl16(gA + 16 * 1024 + k0, lA + 512);
    gl16(gB + k0, lB);
    gl16(gB + 16 * 1024 + k0, lB + 512);
    __syncthreads();
    bf16x8 af[4], bfv[4];
#pragma unroll
    for (int m = 0; m < 4; ++m) af[m]  = *(const bf16x8*)(&As[(wr + m * 16 + fr) * 32 + fk]);
#pragma unroll
    for (int n = 0; n < 4; ++n) bfv[n] = *(const bf16x8*)(&Bs[(wc + n * 16 + fr) * 32 + fk]);
#pragma unroll
    for (int m = 0; m < 4; ++m)
#pragma unroll
      for (int n = 0; n < 4; ++n)
        acc[m][n] = __builtin_amdgcn_mfma_f32_16x16x32_bf16(af[m], bfv[n], acc[m][n], 0, 0, 0);
    __syncthreads();
  }

#pragma unroll
  for (int m = 0; m < 4; ++m)
#pragma unroll
    for (int n = 0; n < 4; ++n)
#pragma unroll
      for (int r = 0; r < 4; ++r) {
        const int grow = bm + wr + m * 16 + (lane >> 4) * 4 + r;
        const int gcol = bn + wc + n * 16 + fr;
        float v = acc[m][n][r];
        const int b_ = grow >> 11, l_ = grow & 2047;
        const int h_ = gcol >> 6,  e_ = gcol & 63;
        if (z == 0) {
          v += pp.bias0[gcol];
          const size_t o = (((size_t)(b_ * 16 + h_) * 2048 + l_) << 6) + e_;
          pp.Qw[o] = f2us(v + pp.rwb[gcol]);
          pp.Qr[o] = f2us(v + pp.rrb[gcol]);
        } else if (z == 1) {
          v += pp.bias1[gcol];
          const size_t o = (((size_t)(b_ * 16 + h_) * 2048 + l_) << 6) + e_;
          pp.Kh[o] = f2us(v);
        } else if (z == 2) {
          v += pp.bias2[gcol];
          const size_t o = (((size_t)(b_ * 16 + h_) * 64 + e_) << 11) + l_;
          pp.Vt[o] = f2us(v);
        } else {
          if (grow < PE_ROWS) {
            const size_t o = ((size_t)h_ * PE_ROWS + grow) * 64 + e_;
            pp.PEh[o] = f2us(v);
          }
        }
      }
}

// ---------------- output projection GEMM (fp32 out, m97 structure) -----------
__global__ __launch_bounds__(256)
void k_gemm_o(const u16* __restrict__ A, const u16* __restrict__ Bt,
              const float* __restrict__ bias, float* __restrict__ outf)
{
  __shared__ __attribute__((aligned(16))) u16 As[128 * 32];
  __shared__ __attribute__((aligned(16))) u16 Bs[128 * 32];
  const int tid  = threadIdx.x;
  const int lane = tid & 63;
  const int wave = tid >> 6;
  const int bm = blockIdx.y * 128;
  const int bn = blockIdx.x * 128;
  const int wr = (wave >> 1) * 64;
  const int wc = (wave & 1) * 64;
  const int fr = lane & 15;
  const int fk = (lane >> 4) * 8;

  f32x4 zero = {0.f, 0.f, 0.f, 0.f};
  f32x4 acc[4][4];
#pragma unroll
  for (int m = 0; m < 4; ++m)
#pragma unroll
    for (int n = 0; n < 4; ++n) acc[m][n] = zero;

  const int cA = wave * 2;
  const u16* gA = A  + (size_t)(bm + cA * 16 + (lane >> 2)) * 1024 + (lane & 3) * 8;
  const u16* gB = Bt + (size_t)(bn + cA * 16 + (lane >> 2)) * 1024 + (lane & 3) * 8;
  u16* lA = As + cA * 512;
  u16* lB = Bs + cA * 512;

  for (int k0 = 0; k0 < 1024; k0 += 32) {
    gl16(gA + k0, lA);
    gl16(gA + 16 * 1024 + k0, lA + 512);
    gl16(gB + k0, lB);
    gl16(gB + 16 * 1024 + k0, lB + 512);
    __syncthreads();
    bf16x8 af[4], bfv[4];
#pragma unroll
    for (int m = 0; m < 4; ++m) af[m]  = *(const bf16x8*)(&As[(wr + m * 16 + fr) * 32 + fk]);
#pragma unroll
    for (int n = 0; n < 4; ++n) bfv[n] = *(const bf16x8*)(&Bs[(wc + n * 16 + fr) * 32 + fk]);
#pragma unroll
    for (int m = 0; m < 4; ++m)
#pragma unroll
      for (int n = 0; n < 4; ++n)
        acc[m][n] = __builtin_amdgcn_mfma_f32_16x16x32_bf16(af[m], bfv[n], acc[m][n], 0, 0, 0);
    __syncthreads();
  }

#pragma unroll
  for (int m = 0; m < 4; ++m)
#pragma unroll
    for (int n = 0; n < 4; ++n)
#pragma unroll
      for (int r = 0; r < 4; ++r) {
        const int grow = bm + wr + m * 16 + (lane >> 4) * 4 + r;
        const int gcol = bn + wc + n * 16 + fr;
        outf[(size_t)grow * 1024 + gcol] = acc[m][n][r] + bias[gcol];
      }
}

// ---------------- fused rel-position causal attention (32x32 swapped) --------
// 1-D grid 512. XCD-locality: hb = (bid&7) + 8*(slot>>4) pins each (h,b)'s 16
// blocks to one XCD (K/V/PE ~3.1MB resident in its 4MB L2). Wave w handles one
// 32-row q-tile; short/long tiles alternate across SIMDs (parity trick).
// All loads hoisted to step top; uniform body (upper half masked when past
// diagonal).
__global__ __launch_bounds__(256, 2)
void k_attn(const u16* __restrict__ Qw, const u16* __restrict__ Qr,
            const u16* __restrict__ Kh, const u16* __restrict__ Vt,
            const u16* __restrict__ PEh, u16* __restrict__ attnb)
{
  const int bid = blockIdx.x;
  const int xcd = bid & 7, slot = bid >> 3;
  const int jb = slot & 15, g = slot >> 4;
  const int hb = xcd + 8 * g;
  const int h = hb & 15, b = hb >> 4;
  const int wave = threadIdx.x >> 6, lane = threadIdx.x & 63;
  const int l31 = lane & 31, hi = lane >> 5;
  const int par = ((slot >> 5) ^ jb) & 1;
  const int tshort = (wave & 2) ? 2 * jb + 1 : 2 * jb;
  const int tlong  = (wave & 2) ? 62 - 2 * jb : 63 - 2 * jb;
  const int qt = ((wave & 1) ^ par) ? tlong : tshort;
  const int q0 = qt * 32;

  const u16* Qw_h = Qw + (size_t)hb * (2048 * 64);
  const u16* Qr_h = Qr + (size_t)hb * (2048 * 64);
  const u16* K_h  = Kh + (size_t)hb * (2048 * 64);
  const u16* V_h  = Vt + (size_t)hb * (64 * 2048);
  const u16* PE_h = PEh + (size_t)h * (PE_ROWS * 64);

  __shared__ float Elds_all[4][32][100];
  float (*Elds)[100] = Elds_all[wave];

  // Q fragments (B-operand: col = lane&31 = q, k = kk*16 + hi*8 + e)
  bf16x8 qwf[4], qrf[4];
#pragma unroll
  for (int kk = 0; kk < 4; ++kk) {
    qwf[kk] = *(const bf16x8*)(Qw_h + (size_t)(q0 + l31) * 64 + kk * 16 + hi * 8);
    qrf[kk] = *(const bf16x8*)(Qr_h + (size_t)(q0 + l31) * 64 + kk * 16 + hi * 8);
  }

  // prologue: carried E tile (rows [Jb0, Jb0+32))
  const int Jb0 = 2017 - q0;
  f32x16 carry = {};
#pragma unroll
  for (int kk = 0; kk < 4; ++kk) {
    bf16x8 pe = *(const bf16x8*)(PE_h + (size_t)(Jb0 + l31) * 64 + kk * 16 + hi * 8);
    carry = mfma32(pe, qrf[kk], carry);
  }

  f32x16 Oac[2] = {};
  float mrun = -1e30f, ls = 0.f;

  for (int c0 = 0; c0 <= q0 + 31; c0 += 64) {
    const int Jb = Jb0 + c0;
    // ---- hoisted loads: PE(tau=1,2), K(both halves), V(8 frags) ----
    bf16x8 pe1[4], pe2[4], kf0[4], kf1[4];
#pragma unroll
    for (int kk = 0; kk < 4; ++kk) {
      const int ko = kk * 16 + hi * 8;
      pe1[kk] = *(const bf16x8*)(PE_h + (size_t)(Jb + 32 + l31) * 64 + ko);
      pe2[kk] = *(const bf16x8*)(PE_h + (size_t)(Jb + 64 + l31) * 64 + ko);
      kf0[kk] = *(const bf16x8*)(K_h + (size_t)(c0 + l31) * 64 + ko);
      kf1[kk] = *(const bf16x8*)(K_h + (size_t)(c0 + 32 + l31) * 64 + ko);
    }
    bf16x8 vfr[2][2][2];
#pragma unroll
    for (int kt = 0; kt < 2; ++kt)
#pragma unroll
      for (int kvs = 0; kvs < 2; ++kvs)
#pragma unroll
        for (int dt = 0; dt < 2; ++dt)
          vfr[kt][kvs][dt] = *(const bf16x8*)(V_h + (size_t)(dt * 32 + l31) * 2048
                                              + c0 + kt * 32 + kvs * 16 + hi * 8);
    // ---- E band: tile0 from carry, tiles 1,2 fresh ----
#pragma unroll
    for (int g4 = 0; g4 < 4; ++g4) {
      float4 w4 = {carry[4 * g4], carry[4 * g4 + 1], carry[4 * g4 + 2], carry[4 * g4 + 3]};
      *(float4*)&Elds[l31][g4 * 8 + hi * 4] = w4;
    }
    {
      f32x16 e1 = {}, e2 = {};
#pragma unroll
      for (int kk = 0; kk < 4; ++kk) e1 = mfma32(pe1[kk], qrf[kk], e1);
#pragma unroll
      for (int kk = 0; kk < 4; ++kk) e2 = mfma32(pe2[kk], qrf[kk], e2);
#pragma unroll
      for (int g4 = 0; g4 < 4; ++g4) {
        float4 w4 = {e1[4 * g4], e1[4 * g4 + 1], e1[4 * g4 + 2], e1[4 * g4 + 3]};
        *(float4*)&Elds[l31][32 + g4 * 8 + hi * 4] = w4;
      }
#pragma unroll
      for (int g4 = 0; g4 < 4; ++g4) {
        float4 w4 = {e2[4 * g4], e2[4 * g4 + 1], e2[4 * g4 + 2], e2[4 * g4 + 3]};
        *(float4*)&Elds[l31][64 + g4 * 8 + hi * 4] = w4;
      }
      carry = e2;
    }
    // ---- QK^T (swapped): S^T[kv][q] ----
    f32x16 s0 = {}, s1 = {};
#pragma unroll
    for (int kk = 0; kk < 4; ++kk) s0 = mfma32(kf0[kk], qwf[kk], s0);
#pragma unroll
    for (int kk = 0; kk < 4; ++kk) s1 = mfma32(kf1[kk], qwf[kk], s1);
    // ---- S assemble: +E (diag read), scale, mask ----
#pragma unroll
    for (int r = 0; r < 16; ++r) {
      const int pat = (r & 3) + 8 * (r >> 2) + 4 * hi;
      float e = Elds[l31][pat + 31 - l31];
      float x = (s0[r] + e) * 0.125f;
      if (c0 + pat > q0 + l31) x = -1e30f;
      s0[r] = x;
    }
#pragma unroll
    for (int r = 0; r < 16; ++r) {
      const int pat = (r & 3) + 8 * (r >> 2) + 4 * hi;
      float e = Elds[l31][32 + pat + 31 - l31];
      float x = (s1[r] + e) * 0.125f;
      if (c0 + 32 + pat > q0 + l31) x = -1e30f;
      s1[r] = x;
    }
    // ---- online softmax (in-lane + one cross-half shuffle) ----
    float mx = fmaxf(s0[0], s1[0]);
#pragma unroll
    for (int r = 1; r < 16; ++r) mx = fmaxf(mx, fmaxf(s0[r], s1[r]));
    mx = fmaxf(mx, __shfl_xor(mx, 32));
    const float mn = fmaxf(mrun, mx);
    const float al = __expf(mrun - mn);
    mrun = mn;

    float rsum = 0.f;
    u32 w0a[8], w1a[8];
#pragma unroll
    for (int g8 = 0; g8 < 8; ++g8) {
      float pa = __expf(s0[2 * g8] - mn);
      float pb = __expf(s0[2 * g8 + 1] - mn);
      u16 ua = f2us(pa), ub = f2us(pb);
      rsum += us2f(ua) + us2f(ub);
      w0a[g8] = (u32)ua | ((u32)ub << 16);
    }
#pragma unroll
    for (int g8 = 0; g8 < 8; ++g8) {
      float pa = __expf(s1[2 * g8] - mn);
      float pb = __expf(s1[2 * g8 + 1] - mn);
      u16 ua = f2us(pa), ub = f2us(pb);
      rsum += us2f(ua) + us2f(ub);
      w1a[g8] = (u32)ua | ((u32)ub << 16);
    }
    ls = ls * al + rsum + __shfl_xor(rsum, 32);
    Oac[0] *= al;
    Oac[1] *= al;

    // ---- PV: build B-frags via half-exchange, A = Vt rows ----
#define PV_KT(WARR, KT)                                                        \
    {                                                                          \
      _Pragma("unroll")                                                        \
      for (int kvs = 0; kvs < 2; ++kvs) {                                      \
        u32 snd0 = hi ? WARR[4 * kvs]     : WARR[4 * kvs + 2];                 \
        u32 snd1 = hi ? WARR[4 * kvs + 1] : WARR[4 * kvs + 3];                 \
        u32 r0 = (u32)__shfl_xor((int)snd0, 32);                               \
        u32 r1 = (u32)__shfl_xor((int)snd1, 32);                               \
        union { u32 u[4]; bf16x8 v; } pf;                                      \
        pf.u[0] = hi ? r0 : WARR[4 * kvs];                                     \
        pf.u[1] = hi ? r1 : WARR[4 * kvs + 1];                                 \
        pf.u[2] = hi ? WARR[4 * kvs + 2] : r0;                                 \
        pf.u[3] = hi ? WARR[4 * kvs + 3] : r1;                                 \
        _Pragma("unroll")                                                      \
        for (int dt = 0; dt < 2; ++dt)                                         \
          Oac[dt] = mfma32(vfr[KT][kvs][dt], pf.v, Oac[dt]);                   \
      }                                                                        \
    }
    PV_KT(w0a, 0)
    PV_KT(w1a, 1)
#undef PV_KT
  }

  // ---- finalize: O^T[d][q] -> attnb[b][q][h*64+d] ----
  const float invl = 1.f / ls;
  const size_t orow = ((size_t)(b * 2048 + q0 + l31)) * 1024 + h * 64;
#pragma unroll
  for (int dt = 0; dt < 2; ++dt)
#pragma unroll
    for (int g4 = 0; g4 < 4; ++g4) {
      ushort4 st;
      st.x = f2us(Oac[dt][4 * g4 + 0] * invl);
      st.y = f2us(Oac[dt][4 * g4 + 1] * invl);
      st.z = f2us(Oac[dt][4 * g4 + 2] * invl);
      st.w = f2us(Oac[dt][4 * g4 + 3] * invl);
      *(ushort4*)(attnb + orow + dt * 32 + g4 * 8 + hi * 4) = st;
    }
}

// ---------------- launch ----------------
extern "C" void kernel_launch(void* const* d_in, const int* in_sizes, int n_in,
                              void* d_out, int out_size, void* d_ws, size_t ws_size,
                              hipStream_t stream)
{
  const float* q   = (const float*)d_in[0];
  const float* k   = (const float*)d_in[1];
  const float* v   = (const float*)d_in[2];
  const float* pos = (const float*)d_in[3];
  const float* Wq  = (const float*)d_in[4];
  const float* bq  = (const float*)d_in[5];
  const float* Wk  = (const float*)d_in[6];
  const float* bk  = (const float*)d_in[7];
  const float* Wv  = (const float*)d_in[8];
  const float* bv  = (const float*)d_in[9];
  const float* Wo  = (const float*)d_in[10];
  const float* bo  = (const float*)d_in[11];
  const float* rwb = (const float*)d_in[12];
  const float* rrb = (const float*)d_in[13];
  const float* rk  = (const float*)d_in[14];

  char* ws = (char*)d_ws;
  u16* qb    = (u16*)(ws + OFF_QB);
  u16* kb    = (u16*)(ws + OFF_KB);
  u16* vb    = (u16*)(ws + OFF_VB);
  u16* Wqt   = (u16*)(ws + OFF_WQT);
  u16* Wkt   = (u16*)(ws + OFF_WKT);
  u16* Wvt   = (u16*)(ws + OFF_WVT);
  u16* Wot   = (u16*)(ws + OFF_WOT);
  u16* Rkt   = (u16*)(ws + OFF_RKT);
  u16* posb  = (u16*)(ws + OFF_POSB);
  u16* Qw    = (u16*)(ws + OFF_QW);
  u16* Qr    = (u16*)(ws + OFF_QR);
  u16* Kh    = (u16*)(ws + OFF_KH);
  u16* Vt    = (u16*)(ws + OFF_VT);
  u16* PEh   = (u16*)(ws + OFF_PEH);
  u16* attnb = (u16*)(ws + OFF_ATTNB);   // aliases qb (dead after Q GEMM)
  float* outf = (float*)d_out;

  // fp32 -> bf16 conversions
  k_f2b4z<<<dim3(4096), 256, 0, stream>>>((const float4*)q, qb, 1048576, 1048576);
  k_f2b4z<<<dim3(4096), 256, 0, stream>>>((const float4*)k, kb, 1048576, 1048576);
  k_f2b4z<<<dim3(4096), 256, 0, stream>>>((const float4*)v, vb, 1048576, 1048576);
  k_f2b4z<<<dim3(2176), 256, 0, stream>>>((const float4*)pos, posb,
                                          (2049 * 1024) / 4, (PE_M * 1024) / 4);
  k_tconv<<<dim3(32, 32), 256, 0, stream>>>(Wq, Wqt);
  k_tconv<<<dim3(32, 32), 256, 0, stream>>>(Wk, Wkt);
  k_tconv<<<dim3(32, 32), 256, 0, stream>>>(Wv, Wvt);
  k_tconv<<<dim3(32, 32), 256, 0, stream>>>(Wo, Wot);
  k_rkt<<<dim3(2, 32, 16), 256, 0, stream>>>(rk, Rkt);

  // fused Q/K/V/PE projections
  ProjPtrs pp;
  pp.A0 = qb;  pp.A1 = kb;  pp.A2 = vb;  pp.A3 = posb;
  pp.B0 = Wqt; pp.B1 = Wkt; pp.B2 = Wvt; pp.B3 = Rkt;
  pp.bias0 = bq; pp.bias1 = bk; pp.bias2 = bv;
  pp.rwb = rwb; pp.rrb = rrb;
  pp.Qw = Qw; pp.Qr = Qr; pp.Kh = Kh; pp.Vt = Vt; pp.PEh = PEh;
  k_gemm_proj<<<dim3(8, 32, 4), 256, 0, stream>>>(pp);

  // fused attention (XCD-local, hoisted-load 32x32 swapped form)
  k_attn<<<dim3(512), 256, 0, stream>>>(Qw, Qr, Kh, Vt, PEh, attnb);

  // output projection (fp32 out)
  k_gemm_o<<<dim3(8, 32), 256, 0, stream>>>(attnb, Wot, bo, outf);
}